// Round 11
// baseline (221.415 us; speedup 1.0000x reference)
//
#include <hip/hip_runtime.h>
#include <hip/hip_bf16.h>

#define CCH 256
#define CQK 32
#define NHW 4096

typedef float f32x4 __attribute__((ext_vector_type(4)));
typedef _Float16 hv8 __attribute__((ext_vector_type(8)));
typedef _Float16 hv4 __attribute__((ext_vector_type(4)));
typedef __fp16 fv2 __attribute__((ext_vector_type(2)));   // cvt_pkrtz native type

// ---------------------------------------------------------------------------
// Prep kernel: convert Wall = concat(b_w, c_w, d_w) fp32 -> fp16 [320][256];
// b_w rows prescaled by log2(e) so QK^T comes out in exp2 units. Grid 80 x 256.
// ---------------------------------------------------------------------------
__global__ __launch_bounds__(256) void prep_kernel(
    const float* __restrict__ b_w, const float* __restrict__ c_w,
    const float* __restrict__ d_w, _Float16* __restrict__ Wh)
{
    const int bid = blockIdx.x, tid = threadIdx.x;
    const int idx = (bid * 256 + tid) * 4;
    const int row = idx >> 8, col = idx & 255;
    const float* src = (row < 32) ? (b_w + row * CCH + col)
                     : (row < 64) ? (c_w + (row - 32) * CCH + col)
                                  : (d_w + (row - 64) * CCH + col);
    const float scl = (row < 32) ? 1.4426950408889634f : 1.0f;
    float4 v = *reinterpret_cast<const float4*>(src);
    _Float16* dst = Wh + (size_t)row * CCH + col;
    dst[0] = (_Float16)(v.x * scl); dst[1] = (_Float16)(v.y * scl);
    dst[2] = (_Float16)(v.z * scl); dst[3] = (_Float16)(v.w * scl);
}

// ---------------------------------------------------------------------------
// Projection kernel v2 (R10 verified): MFMA loop + LDS-staged coalesced
// epilogue. bqT/ckT = one contiguous 2KB burst per block; dv = 64B row
// bursts. Biases applied in-register before staging.
// ---------------------------------------------------------------------------
__global__ __launch_bounds__(256) void proj_kernel(
    const float* __restrict__ a, const _Float16* __restrict__ Wh,
    const float* __restrict__ b_b, const float* __restrict__ c_b,
    const float* __restrict__ d_b,
    _Float16* __restrict__ bqT, _Float16* __restrict__ ckT,
    _Float16* __restrict__ dv)
{
    __shared__ _Float16 aT[32][CCH + 24];   // [pos][ch] input transpose
    __shared__ _Float16 oT[256][34];        // dv staging [ch][pos]
    __shared__ _Float16 pqT[32][34];        // bq staging [pos][ch]
    __shared__ _Float16 pkT[32][34];        // ck staging [pos][ch]

    const int n    = blockIdx.x >> 7;
    const int i0   = (blockIdx.x & 127) << 5;
    const int tid  = threadIdx.x;
    const int lane = tid & 63;
    const int wave = tid >> 6;
    const int l15  = lane & 15;
    const int quad = lane >> 4;

    {
        const float* ap = a + (size_t)(n*CCH + tid)*NHW + i0;
        #pragma unroll
        for (int j = 0; j < 8; ++j) {
            float4 v = *reinterpret_cast<const float4*>(ap + j*4);
            aT[j*4+0][tid] = (_Float16)v.x;
            aT[j*4+1][tid] = (_Float16)v.y;
            aT[j*4+2][tid] = (_Float16)v.z;
            aT[j*4+3][tid] = (_Float16)v.w;
        }
    }
    __syncthreads();

    const f32x4 zf = {0.f, 0.f, 0.f, 0.f};
    f32x4 acc[5][2];
    #pragma unroll
    for (int t = 0; t < 5; ++t) { acc[t][0] = zf; acc[t][1] = zf; }

    const int ch0w = wave * 80;

    #pragma unroll
    for (int ks = 0; ks < 8; ++ks) {
        const int k0 = ks * 32;
        hv8 af0 = *reinterpret_cast<const hv8*>(&aT[l15][k0 + quad*8]);
        hv8 af1 = *reinterpret_cast<const hv8*>(&aT[16 + l15][k0 + quad*8]);
        #pragma unroll
        for (int t = 0; t < 5; ++t) {
            const int ch0 = ch0w + t*16;
            hv8 bf = *reinterpret_cast<const hv8*>(
                Wh + (size_t)(ch0 + l15)*CCH + k0 + quad*8);
            acc[t][0] = __builtin_amdgcn_mfma_f32_16x16x32_f16(af0, bf, acc[t][0], 0, 0, 0);
            acc[t][1] = __builtin_amdgcn_mfma_f32_16x16x32_f16(af1, bf, acc[t][1], 0, 0, 0);
        }
    }

    // ---- stage results into LDS (biases applied here)
    const int posq = quad*4;                // local pos base
    #pragma unroll
    for (int t = 0; t < 5; ++t) {
        const int ch0 = ch0w + t*16;
        if (ch0 < 64) {
            const float* bias_arr = (ch0 < 32) ? b_b : c_b;
            const int    ch       = (ch0 & 31) + l15;
            const float  bias     = bias_arr[ch] *
                ((ch0 < 32) ? 1.4426950408889634f : 1.0f);
            #pragma unroll
            for (int nf = 0; nf < 2; ++nf) {
                #pragma unroll
                for (int r = 0; r < 4; ++r) {
                    const int pos = posq + nf*16 + r;
                    if (ch0 < 32) pqT[pos][ch] = (_Float16)(acc[t][nf][r] + bias);
                    else          pkT[pos][ch] = (_Float16)(acc[t][nf][r] + bias);
                }
            }
        } else {
            const int ch   = ch0 - 64 + l15;
            const float bias = d_b[ch];
            #pragma unroll
            for (int nf = 0; nf < 2; ++nf) {
                hv4 v = { (_Float16)(acc[t][nf][0] + bias),
                          (_Float16)(acc[t][nf][1] + bias),
                          (_Float16)(acc[t][nf][2] + bias),
                          (_Float16)(acc[t][nf][3] + bias) };
                *reinterpret_cast<hv4*>(&oT[ch][posq + nf*16]) = v;
            }
        }
    }
    __syncthreads();

    // ---- coalesced global writes
    {
        const int p   = (tid & 127) >> 2;
        const int seg = (tid & 3) << 3;
        if (tid < 128) {
            *reinterpret_cast<int4*>(
                bqT + ((size_t)n*NHW + i0 + p)*CQK + seg) =
                *reinterpret_cast<const int4*>(&pqT[p][seg]);
        } else {
            *reinterpret_cast<int4*>(
                ckT + ((size_t)n*NHW + i0 + p)*CQK + seg) =
                *reinterpret_cast<const int4*>(&pkT[p][seg]);
        }
    }
    #pragma unroll
    for (int pass = 0; pass < 4; ++pass) {
        const int row = pass*64 + (tid >> 2);
        const int seg = (tid & 3) << 3;
        *reinterpret_cast<int4*>(
            dv + ((size_t)(n*CCH + row))*NHW + i0 + seg) =
            *reinterpret_cast<const int4*>(&oT[row][seg]);
    }
}

// ---------------------------------------------------------------------------
// Pass B v10: R8 structure + REGISTER-STAGED V (T14 issue-early/write-late).
// The global_load_lds DMA issued right before its draining barrier exposed
// ~900 cyc/iter. Now: 8 global_load_dwordx4 into VGPRs issued at the TOP of
// the iteration (latency hidden under PV+softmax), then after the
// all-readers-done barrier the registers are ds_write_b128'd into vbuf
// (lgkm-only, ~150 cyc) and the second barrier publishes them. KT=64,
// k-split 4, q/wave=64, online softmax + defer-max, both-sides XOR swizzle,
// P via p_lds -- all byte-identical addressing to the verified R8/R10 kernel.
// smem carve (143360 B): vbuf 4x16384 | p 8x4x2304 | lbuf 2048 | mbuf 2048.
// ---------------------------------------------------------------------------
__global__ __launch_bounds__(512, 2) void attn_kernel(
    const _Float16* __restrict__ bqT, const _Float16* __restrict__ ckT,
    const _Float16* __restrict__ dv,
    const float* __restrict__ a, const float* __restrict__ alpha_p,
    float* __restrict__ out)
{
    __shared__ __align__(16) char smem[143360];

    // XCD swizzle: 256 blocks, 8 XCDs -> XCD k owns logical [k*32,(k+1)*32)
    const int bx   = ((blockIdx.x & 7) << 5) | (blockIdx.x >> 3);
    const int n    = bx >> 6;
    const int cg   = (bx >> 5) & 1;
    const int qt   = bx & 31;
    const int q0b  = qt << 7;           // block covers 128 q
    const int co0  = cg << 7;           // 128 output channels
    const int tid  = threadIdx.x;
    const int wave = tid >> 6;
    const int g    = wave >> 1;         // k-group 0..3, keys [g*1024,(g+1)*1024)
    const int qw   = wave & 1;          // q-half (64 q) within block
    const int lane = tid & 63;
    const int l15  = lane & 15;
    const int quad = lane >> 4;
    const int kg0  = g << 10;

    _Float16* vbuf = (_Float16*)(smem + (g << 14));          // [128 co][64 k], swizzled
    _Float16* pb   = (_Float16*)(smem + 65536 + wave*9216);  // 4 slabs of [16][72]
    float*    lbuf = (float*)(smem + 139264);                // [4 g][128 q] l partials
    float*    mbuf = (float*)(smem + 141312);                // [4 g][128 q] m partials

    const f32x4 zf = {0.f, 0.f, 0.f, 0.f};
    const _Float16 one_h = (_Float16)1.0f;
    const hv8 ones = { one_h, one_h, one_h, one_h, one_h, one_h, one_h, one_h };

    // q fragments, 4 groups of 16 q
    hv8 qf[4];
    #pragma unroll
    for (int X = 0; X < 4; ++X) {
        const int q = q0b + qw*64 + X*16 + l15;
        qf[X] = *reinterpret_cast<const hv8*>(
            bqT + ((size_t)n*NHW + q)*CQK + quad*8);
    }

    // kf base for this lane within this group's key range
    const _Float16* ckbase = ckT + ((size_t)(n*NHW + kg0 + l15))*CQK + quad*8;

    // online-softmax state: mneg[X] = -(running max of q=l15), in log2 units
    float mneg[4] = {0.f, 0.f, 0.f, 0.f};

    f32x4 acc[4][8];
    #pragma unroll
    for (int X = 0; X < 4; ++X)
        #pragma unroll
        for (int t = 0; t < 8; ++t) acc[X][t] = zf;
    f32x4 accL[4];
    #pragma unroll
    for (int X = 0; X < 4; ++X) accL[X] = zf;

    // ---- staging addresses (identical to R8's gll16 source/dest layout):
    // lane i covers row qw*64 + j*8 + (i>>3), 16B slot (i&7), source column
    // pre-permuted 8*((i&7)^(i>>3)); LDS dest = base + j*1024B + lane*16B.
    const int rl8 = lane >> 3;
    const _Float16* dvs = dv
        + (size_t)(n*CCH + co0 + qw*64 + rl8)*NHW + kg0 + 8*((lane & 7) ^ rl8);
    _Float16* ldsb = (_Float16*)(smem + (g << 14) + qw*8192);

    // swizzled V read offsets (halves)
    const int c0h = ((quad*16) ^ ((l15 & 7) << 4)) >> 1;
    const int c1h = ((64 + quad*16) ^ ((l15 & 7) << 4)) >> 1;

    // S^T/exp (online) for one key tile, all 4 q-groups -> pb
    auto softmax_tile = [&](const hv8* kf) {
        #pragma unroll
        for (int X = 0; X < 4; ++X) {
            const f32x4 minit = {mneg[X], mneg[X], mneg[X], mneg[X]};
            f32x4 s0 = __builtin_amdgcn_mfma_f32_16x16x32_f16(kf[0], qf[X], minit, 0, 0, 0);
            f32x4 s1 = __builtin_amdgcn_mfma_f32_16x16x32_f16(kf[1], qf[X], minit, 0, 0, 0);
            f32x4 s2 = __builtin_amdgcn_mfma_f32_16x16x32_f16(kf[2], qf[X], minit, 0, 0, 0);
            f32x4 s3 = __builtin_amdgcn_mfma_f32_16x16x32_f16(kf[3], qf[X], minit, 0, 0, 0);
            // tile max for q=l15 (reduce 16 regs, then across quads)
            float tm = fmaxf(
                fmaxf(fmaxf(fmaxf(s0[0], s0[1]), fmaxf(s0[2], s0[3])),
                      fmaxf(fmaxf(s1[0], s1[1]), fmaxf(s1[2], s1[3]))),
                fmaxf(fmaxf(fmaxf(s2[0], s2[1]), fmaxf(s2[2], s2[3])),
                      fmaxf(fmaxf(s3[0], s3[1]), fmaxf(s3[2], s3[3]))));
            tm = fmaxf(tm, __shfl_xor(tm, 16, 64));
            tm = fmaxf(tm, __shfl_xor(tm, 32, 64));
            const float upd = (tm > 8.0f) ? tm : 0.0f;
            if (__any(upd > 0.0f)) {
                const float sc = __builtin_amdgcn_exp2f(-upd);   // at q=l15
                // gather scales to acc's row mapping (q = quad*4+r)
                float s_r0 = __shfl(sc, quad*4 + 0, 64);
                float s_r1 = __shfl(sc, quad*4 + 1, 64);
                float s_r2 = __shfl(sc, quad*4 + 2, 64);
                float s_r3 = __shfl(sc, quad*4 + 3, 64);
                #pragma unroll
                for (int t = 0; t < 8; ++t) {
                    acc[X][t][0] *= s_r0; acc[X][t][1] *= s_r1;
                    acc[X][t][2] *= s_r2; acc[X][t][3] *= s_r3;
                }
                accL[X][0] *= s_r0; accL[X][1] *= s_r1;
                accL[X][2] *= s_r2; accL[X][3] *= s_r3;
                mneg[X] -= upd;
                s0[0] -= upd; s0[1] -= upd; s0[2] -= upd; s0[3] -= upd;
                s1[0] -= upd; s1[1] -= upd; s1[2] -= upd; s1[3] -= upd;
                s2[0] -= upd; s2[1] -= upd; s2[2] -= upd; s2[3] -= upd;
                s3[0] -= upd; s3[1] -= upd; s3[2] -= upd; s3[3] -= upd;
            }
            const f32x4 sv[4] = {s0, s1, s2, s3};
            #pragma unroll
            for (int f = 0; f < 4; ++f) {
                float p0 = __builtin_amdgcn_exp2f(sv[f][0]);
                float p1 = __builtin_amdgcn_exp2f(sv[f][1]);
                float p2 = __builtin_amdgcn_exp2f(sv[f][2]);
                float p3 = __builtin_amdgcn_exp2f(sv[f][3]);
                fv2 lo = __builtin_amdgcn_cvt_pkrtz(p0, p1);
                fv2 hi = __builtin_amdgcn_cvt_pkrtz(p2, p3);
                uint2 w;
                w.x = __builtin_bit_cast(unsigned, lo);
                w.y = __builtin_bit_cast(unsigned, hi);
                *reinterpret_cast<uint2*>(
                    pb + X*1152 + l15*72 + f*16 + quad*4) = w;
            }
        }
    };

    hv8 pf0[4], pf1[4];
    auto read_pf = [&]() {
        #pragma unroll
        for (int X = 0; X < 4; ++X) {
            pf0[X] = *reinterpret_cast<const hv8*>(pb + X*1152 + l15*72 + quad*8);
            pf1[X] = *reinterpret_cast<const hv8*>(pb + X*1152 + l15*72 + 32 + quad*8);
        }
    };

    int4 vreg[8];
    auto load_v = [&](int kt) {
        #pragma unroll
        for (int j = 0; j < 8; ++j)
            vreg[j] = *reinterpret_cast<const int4*>(
                dvs + (size_t)(j*8)*NHW + kt*64);
    };
    auto store_v = [&]() {
        #pragma unroll
        for (int j = 0; j < 8; ++j)
            *reinterpret_cast<int4*>(ldsb + (size_t)j*512 + lane*8) = vreg[j];
    };

    auto load_kf = [&](int key0, hv8* kf) {
        #pragma unroll
        for (int f = 0; f < 4; ++f)
            kf[f] = *reinterpret_cast<const hv8*>(
                ckbase + (size_t)(key0 + f*16)*CQK);
    };

    // ---- prologue: V(0) -> regs -> LDS, softmax(0), pf(0)
    {
        load_v(0);
        hv8 kf0[4];
        load_kf(0, kf0);
        softmax_tile(kf0);
        read_pf();
        store_v();
    }
    __syncthreads();    // V(0) visible

    for (int kt = 0; kt < 16; ++kt) {
        hv8 kfn[4];
        if (kt < 15) {
            load_v(kt + 1);            // ISSUE EARLY: hidden under PV+softmax
            load_kf((kt + 1)*64, kfn);
        }

        // ---- PV(kt): each V fragment feeds 4 q-groups
        #pragma unroll
        for (int t = 0; t < 8; ++t) {
            const _Float16* vr = vbuf + (t*16 + l15)*64;
            hv8 d0 = *reinterpret_cast<const hv8*>(vr + c0h);
            #pragma unroll
            for (int X = 0; X < 4; ++X)
                acc[X][t] = __builtin_amdgcn_mfma_f32_16x16x32_f16(
                    pf0[X], d0, acc[X][t], 0, 0, 0);
            hv8 d1 = *reinterpret_cast<const hv8*>(vr + c1h);
            #pragma unroll
            for (int X = 0; X < 4; ++X)
                acc[X][t] = __builtin_amdgcn_mfma_f32_16x16x32_f16(
                    pf1[X], d1, acc[X][t], 0, 0, 0);
        }
        #pragma unroll
        for (int X = 0; X < 4; ++X) {
            accL[X] = __builtin_amdgcn_mfma_f32_16x16x32_f16(pf0[X], ones, accL[X], 0, 0, 0);
            accL[X] = __builtin_amdgcn_mfma_f32_16x16x32_f16(pf1[X], ones, accL[X], 0, 0, 0);
        }

        if (kt < 15) {
            softmax_tile(kfn);          // p(kt+1) -> pb (own wave region)
            read_pf();                  // pf(kt+1), same-wave order
            __syncthreads();            // all waves done READING V(kt)
            store_v();                  // regs -> vbuf (loads long complete)
            __syncthreads();            // V(kt+1) visible
        }
    }

    // ---- align k-group partials to the common max, merge, epilogue
    if (lane < 16) {
        #pragma unroll
        for (int X = 0; X < 4; ++X)
            mbuf[g*128 + qw*64 + X*16 + l15] = -mneg[X];
    }
    __syncthreads();            // all waves past loop; mbuf complete

    {
        #pragma unroll
        for (int X = 0; X < 4; ++X) {
            const int qloc = qw*64 + X*16 + quad*4;
            float4 m0 = *reinterpret_cast<float4*>(&mbuf[0*128 + qloc]);
            float4 m1 = *reinterpret_cast<float4*>(&mbuf[1*128 + qloc]);
            float4 m2 = *reinterpret_cast<float4*>(&mbuf[2*128 + qloc]);
            float4 m3 = *reinterpret_cast<float4*>(&mbuf[3*128 + qloc]);
            float4 mm;
            mm.x = fmaxf(fmaxf(m0.x, m1.x), fmaxf(m2.x, m3.x));
            mm.y = fmaxf(fmaxf(m0.y, m1.y), fmaxf(m2.y, m3.y));
            mm.z = fmaxf(fmaxf(m0.z, m1.z), fmaxf(m2.z, m3.z));
            mm.w = fmaxf(fmaxf(m0.w, m1.w), fmaxf(m2.w, m3.w));
            float4 mo = (g == 0) ? m0 : (g == 1) ? m1 : (g == 2) ? m2 : m3;
            float sc0 = __builtin_amdgcn_exp2f(mo.x - mm.x);
            float sc1 = __builtin_amdgcn_exp2f(mo.y - mm.y);
            float sc2 = __builtin_amdgcn_exp2f(mo.z - mm.z);
            float sc3 = __builtin_amdgcn_exp2f(mo.w - mm.w);
            #pragma unroll
            for (int t = 0; t < 8; ++t) {
                acc[X][t][0] *= sc0; acc[X][t][1] *= sc1;
                acc[X][t][2] *= sc2; acc[X][t][3] *= sc3;
            }
            accL[X][0] *= sc0; accL[X][1] *= sc1;
            accL[X][2] *= sc2; accL[X][3] *= sc3;
        }
    }

    float* buf1 = (float*)smem;                   // [128 co][132 q]
    float* buf2 = (float*)(smem + 67584);

    if (l15 == 0) {
        #pragma unroll
        for (int X = 0; X < 4; ++X)
            *reinterpret_cast<float4*>(&lbuf[g*128 + qw*64 + X*16 + quad*4]) =
                *reinterpret_cast<float4*>(&accL[X]);
    }
    // Round A: g1 -> buf1, g3 -> buf2
    if (g == 1 || g == 3) {
        float* b = (g == 1) ? buf1 : buf2;
        #pragma unroll
        for (int X = 0; X < 4; ++X)
            #pragma unroll
            for (int t = 0; t < 8; ++t)
                *reinterpret_cast<float4*>(
                    &b[(t*16 + l15)*132 + qw*64 + X*16 + quad*4]) =
                    *reinterpret_cast<float4*>(&acc[X][t]);
    }
    __syncthreads();
    if (g == 0 || g == 2) {
        float* b = (g == 0) ? buf1 : buf2;
        #pragma unroll
        for (int X = 0; X < 4; ++X)
            #pragma unroll
            for (int t = 0; t < 8; ++t) {
                float4 p = *reinterpret_cast<float4*>(
                    &b[(t*16 + l15)*132 + qw*64 + X*16 + quad*4]);
                acc[X][t][0] += p.x; acc[X][t][1] += p.y;
                acc[X][t][2] += p.z; acc[X][t][3] += p.w;
            }
    }
    __syncthreads();
    // Round B: g2 -> buf1
    if (g == 2) {
        #pragma unroll
        for (int X = 0; X < 4; ++X)
            #pragma unroll
            for (int t = 0; t < 8; ++t)
                *reinterpret_cast<float4*>(
                    &buf1[(t*16 + l15)*132 + qw*64 + X*16 + quad*4]) =
                    *reinterpret_cast<float4*>(&acc[X][t]);
    }
    __syncthreads();
    if (g == 0) {
        const float alpha = alpha_p[0];
        #pragma unroll
        for (int X = 0; X < 4; ++X) {
            const int qlocX = qw*64 + X*16 + quad*4;
            #pragma unroll
            for (int t = 0; t < 8; ++t) {
                float4 p = *reinterpret_cast<float4*>(
                    &buf1[(t*16 + l15)*132 + qlocX]);
                acc[X][t][0] += p.x; acc[X][t][1] += p.y;
                acc[X][t][2] += p.z; acc[X][t][3] += p.w;
            }
            float4 l0 = *reinterpret_cast<float4*>(&lbuf[0*128 + qlocX]);
            float4 l1 = *reinterpret_cast<float4*>(&lbuf[1*128 + qlocX]);
            float4 l2 = *reinterpret_cast<float4*>(&lbuf[2*128 + qlocX]);
            float4 l3 = *reinterpret_cast<float4*>(&lbuf[3*128 + qlocX]);
            f32x4 rl;
            rl[0] = alpha / (l0.x + l1.x + l2.x + l3.x);
            rl[1] = alpha / (l0.y + l1.y + l2.y + l3.y);
            rl[2] = alpha / (l0.z + l1.z + l2.z + l3.z);
            rl[3] = alpha / (l0.w + l1.w + l2.w + l3.w);
            #pragma unroll
            for (int t = 0; t < 8; ++t) {
                const size_t off =
                    ((size_t)(n*CCH + co0 + t*16 + l15))*NHW + q0b + qlocX;
                float4 av = *reinterpret_cast<const float4*>(a + off);
                float4 o;
                o.x = acc[X][t][0]*rl[0] + av.x;
                o.y = acc[X][t][1]*rl[1] + av.y;
                o.z = acc[X][t][2]*rl[2] + av.z;
                o.w = acc[X][t][3]*rl[3] + av.w;
                *reinterpret_cast<float4*>(out + off) = o;
            }
        }
    }
}

extern "C" void kernel_launch(void* const* d_in, const int* in_sizes, int n_in,
                              void* d_out, int out_size, void* d_ws, size_t ws_size,
                              hipStream_t stream)
{
    const float* a    = (const float*)d_in[0];
    const float* b_w  = (const float*)d_in[1];
    const float* b_b  = (const float*)d_in[2];
    const float* c_w  = (const float*)d_in[3];
    const float* c_b  = (const float*)d_in[4];
    const float* d_w  = (const float*)d_in[5];
    const float* d_b  = (const float*)d_in[6];
    const float* alp  = (const float*)d_in[7];
    float* out = (float*)d_out;

    _Float16* bqT  = (_Float16*)d_ws;                 // [4][4096][32] fp16, 1 MB
    _Float16* ckT  = bqT + (size_t)4*NHW*CQK;         // [4][4096][32] fp16, 1 MB
    _Float16* dv   = ckT + (size_t)4*NHW*CQK;         // [4][256][4096] fp16, 8 MB
    _Float16* Wh   = dv + (size_t)4*CCH*NHW;          // [320][256] fp16, 160 KB

    prep_kernel<<<80, 256, 0, stream>>>(b_w, c_w, d_w, Wh);
    proj_kernel<<<512, 256, 0, stream>>>(a, Wh, b_b, c_b, d_b, bqT, ckT, dv);
    attn_kernel<<<256, 512, 0, stream>>>(bqT, ckT, dv, a, alp, out);
}

// Round 12
// 164.635 us; speedup vs baseline: 1.3449x; 1.3449x over previous
//
#include <hip/hip_runtime.h>
#include <hip/hip_bf16.h>

#define CCH 256
#define CQK 32
#define NHW 4096

typedef float f32x4 __attribute__((ext_vector_type(4)));
typedef _Float16 hv8 __attribute__((ext_vector_type(8)));
typedef _Float16 hv4 __attribute__((ext_vector_type(4)));
typedef __fp16 fv2 __attribute__((ext_vector_type(2)));   // cvt_pkrtz native type

// Direct global->LDS DMA, 16 B/lane. LDS dest = wave-uniform base + lane*16.
typedef __attribute__((address_space(3))) unsigned int lds_u32_t;
typedef __attribute__((address_space(1))) const unsigned int glb_u32_t;
__device__ __forceinline__ void gll16(const _Float16* gp, _Float16* lp) {
    __builtin_amdgcn_global_load_lds((glb_u32_t*)gp, (lds_u32_t*)lp, 16, 0, 0);
}

// ---------------------------------------------------------------------------
// Prep kernel: convert Wall = concat(b_w, c_w, d_w) fp32 -> fp16 [320][256];
// b_w rows prescaled by log2(e) so QK^T comes out in exp2 units. Grid 80 x 256.
// ---------------------------------------------------------------------------
__global__ __launch_bounds__(256) void prep_kernel(
    const float* __restrict__ b_w, const float* __restrict__ c_w,
    const float* __restrict__ d_w, _Float16* __restrict__ Wh)
{
    const int bid = blockIdx.x, tid = threadIdx.x;
    const int idx = (bid * 256 + tid) * 4;
    const int row = idx >> 8, col = idx & 255;
    const float* src = (row < 32) ? (b_w + row * CCH + col)
                     : (row < 64) ? (c_w + (row - 32) * CCH + col)
                                  : (d_w + (row - 64) * CCH + col);
    const float scl = (row < 32) ? 1.4426950408889634f : 1.0f;
    float4 v = *reinterpret_cast<const float4*>(src);
    _Float16* dst = Wh + (size_t)row * CCH + col;
    dst[0] = (_Float16)(v.x * scl); dst[1] = (_Float16)(v.y * scl);
    dst[2] = (_Float16)(v.z * scl); dst[3] = (_Float16)(v.w * scl);
}

// ---------------------------------------------------------------------------
// Projection kernel v2 (R10 verified): MFMA loop + LDS-staged coalesced
// epilogue. bqT/ckT = one contiguous 2KB burst per block; dv = 64B row
// bursts. Biases applied in-register before staging.
// ---------------------------------------------------------------------------
__global__ __launch_bounds__(256) void proj_kernel(
    const float* __restrict__ a, const _Float16* __restrict__ Wh,
    const float* __restrict__ b_b, const float* __restrict__ c_b,
    const float* __restrict__ d_b,
    _Float16* __restrict__ bqT, _Float16* __restrict__ ckT,
    _Float16* __restrict__ dv)
{
    __shared__ _Float16 aT[32][CCH + 24];   // [pos][ch] input transpose
    __shared__ _Float16 oT[256][34];        // dv staging [ch][pos]
    __shared__ _Float16 pqT[32][34];        // bq staging [pos][ch]
    __shared__ _Float16 pkT[32][34];        // ck staging [pos][ch]

    const int n    = blockIdx.x >> 7;
    const int i0   = (blockIdx.x & 127) << 5;
    const int tid  = threadIdx.x;
    const int lane = tid & 63;
    const int wave = tid >> 6;
    const int l15  = lane & 15;
    const int quad = lane >> 4;

    {
        const float* ap = a + (size_t)(n*CCH + tid)*NHW + i0;
        #pragma unroll
        for (int j = 0; j < 8; ++j) {
            float4 v = *reinterpret_cast<const float4*>(ap + j*4);
            aT[j*4+0][tid] = (_Float16)v.x;
            aT[j*4+1][tid] = (_Float16)v.y;
            aT[j*4+2][tid] = (_Float16)v.z;
            aT[j*4+3][tid] = (_Float16)v.w;
        }
    }
    __syncthreads();

    const f32x4 zf = {0.f, 0.f, 0.f, 0.f};
    f32x4 acc[5][2];
    #pragma unroll
    for (int t = 0; t < 5; ++t) { acc[t][0] = zf; acc[t][1] = zf; }

    const int ch0w = wave * 80;

    #pragma unroll
    for (int ks = 0; ks < 8; ++ks) {
        const int k0 = ks * 32;
        hv8 af0 = *reinterpret_cast<const hv8*>(&aT[l15][k0 + quad*8]);
        hv8 af1 = *reinterpret_cast<const hv8*>(&aT[16 + l15][k0 + quad*8]);
        #pragma unroll
        for (int t = 0; t < 5; ++t) {
            const int ch0 = ch0w + t*16;
            hv8 bf = *reinterpret_cast<const hv8*>(
                Wh + (size_t)(ch0 + l15)*CCH + k0 + quad*8);
            acc[t][0] = __builtin_amdgcn_mfma_f32_16x16x32_f16(af0, bf, acc[t][0], 0, 0, 0);
            acc[t][1] = __builtin_amdgcn_mfma_f32_16x16x32_f16(af1, bf, acc[t][1], 0, 0, 0);
        }
    }

    // ---- stage results into LDS (biases applied here)
    const int posq = quad*4;                // local pos base
    #pragma unroll
    for (int t = 0; t < 5; ++t) {
        const int ch0 = ch0w + t*16;
        if (ch0 < 64) {
            const float* bias_arr = (ch0 < 32) ? b_b : c_b;
            const int    ch       = (ch0 & 31) + l15;
            const float  bias     = bias_arr[ch] *
                ((ch0 < 32) ? 1.4426950408889634f : 1.0f);
            #pragma unroll
            for (int nf = 0; nf < 2; ++nf) {
                #pragma unroll
                for (int r = 0; r < 4; ++r) {
                    const int pos = posq + nf*16 + r;
                    if (ch0 < 32) pqT[pos][ch] = (_Float16)(acc[t][nf][r] + bias);
                    else          pkT[pos][ch] = (_Float16)(acc[t][nf][r] + bias);
                }
            }
        } else {
            const int ch   = ch0 - 64 + l15;
            const float bias = d_b[ch];
            #pragma unroll
            for (int nf = 0; nf < 2; ++nf) {
                hv4 v = { (_Float16)(acc[t][nf][0] + bias),
                          (_Float16)(acc[t][nf][1] + bias),
                          (_Float16)(acc[t][nf][2] + bias),
                          (_Float16)(acc[t][nf][3] + bias) };
                *reinterpret_cast<hv4*>(&oT[ch][posq + nf*16]) = v;
            }
        }
    }
    __syncthreads();

    // ---- coalesced global writes
    {
        const int p   = (tid & 127) >> 2;
        const int seg = (tid & 3) << 3;
        if (tid < 128) {
            *reinterpret_cast<int4*>(
                bqT + ((size_t)n*NHW + i0 + p)*CQK + seg) =
                *reinterpret_cast<const int4*>(&pqT[p][seg]);
        } else {
            *reinterpret_cast<int4*>(
                ckT + ((size_t)n*NHW + i0 + p)*CQK + seg) =
                *reinterpret_cast<const int4*>(&pkT[p][seg]);
        }
    }
    #pragma unroll
    for (int pass = 0; pass < 4; ++pass) {
        const int row = pass*64 + (tid >> 2);
        const int seg = (tid & 3) << 3;
        *reinterpret_cast<int4*>(
            dv + ((size_t)(n*CCH + row))*NHW + i0 + seg) =
            *reinterpret_cast<const int4*>(&oT[row][seg]);
    }
}

// ---------------------------------------------------------------------------
// Pass B v11: R6's fast branch-free inner loop + BATCHED per-group row-max
// prologue. R11's reg-staging spilled (acc = 128 AGPR + 128 VGPR = the full
// 256-reg budget at 2 waves/SIMD -> WRITE_SIZE 18.7->155MB): reverted.
// R8's online softmax cost ~8us of in-loop serial chain (tile-max fmax tree
// + __any branch + shfls every tile); replaced by a FIXED per-group max:
// prologue computes max over this group's 1024 keys with 8-wide batched L2
// loads (8 independent kf in flight -> ~1.5us, vs R7's serial 8.4us), then
// the loop uses constant minit (no branches). The R8 merge epilogue already
// aligns differing per-group maxima -- unchanged. V staging via
// global_load_lds (no registers), KT=64, k-split 4, q/wave=64, both-sides
// XOR swizzle, P via p_lds.
// smem carve (143360 B): vbuf 4x16384 | p 8x4x2304 | lbuf 2048 | mbuf 2048.
// ---------------------------------------------------------------------------
__global__ __launch_bounds__(512, 2) void attn_kernel(
    const _Float16* __restrict__ bqT, const _Float16* __restrict__ ckT,
    const _Float16* __restrict__ dv,
    const float* __restrict__ a, const float* __restrict__ alpha_p,
    float* __restrict__ out)
{
    __shared__ __align__(16) char smem[143360];

    // XCD swizzle: 256 blocks, 8 XCDs -> XCD k owns logical [k*32,(k+1)*32)
    const int bx   = ((blockIdx.x & 7) << 5) | (blockIdx.x >> 3);
    const int n    = bx >> 6;
    const int cg   = (bx >> 5) & 1;
    const int qt   = bx & 31;
    const int q0b  = qt << 7;           // block covers 128 q
    const int co0  = cg << 7;           // 128 output channels
    const int tid  = threadIdx.x;
    const int wave = tid >> 6;
    const int g    = wave >> 1;         // k-group 0..3, keys [g*1024,(g+1)*1024)
    const int qw   = wave & 1;          // q-half (64 q) within block
    const int lane = tid & 63;
    const int l15  = lane & 15;
    const int quad = lane >> 4;
    const int kg0  = g << 10;

    _Float16* vbuf = (_Float16*)(smem + (g << 14));          // [128 co][64 k], swizzled
    _Float16* pb   = (_Float16*)(smem + 65536 + wave*9216);  // 4 slabs of [16][72]
    float*    lbuf = (float*)(smem + 139264);                // [4 g][128 q] l partials
    float*    mbuf = (float*)(smem + 141312);                // [4 g][128 q] m partials

    const f32x4 zf = {0.f, 0.f, 0.f, 0.f};
    const _Float16 one_h = (_Float16)1.0f;
    const hv8 ones = { one_h, one_h, one_h, one_h, one_h, one_h, one_h, one_h };

    // q fragments, 4 groups of 16 q
    hv8 qf[4];
    #pragma unroll
    for (int X = 0; X < 4; ++X) {
        const int q = q0b + qw*64 + X*16 + l15;
        qf[X] = *reinterpret_cast<const hv8*>(
            bqT + ((size_t)n*NHW + q)*CQK + quad*8);
    }

    // kf base for this lane within this group's key range
    const _Float16* ckbase = ckT + ((size_t)(n*NHW + kg0 + l15))*CQK + quad*8;

    // ---- batched per-group row-max prologue: 8 batches x 8 kf (1024 keys).
    //      8 independent 16B loads in flight per batch; tree-fmax (shallow).
    //      Runs before acc is live -> kb[8] has register headroom.
    float mneg[4];
    {
        float mx[4] = {-1e30f, -1e30f, -1e30f, -1e30f};
        #pragma unroll
        for (int bt = 0; bt < 8; ++bt) {
            hv8 kb[8];
            #pragma unroll
            for (int j = 0; j < 8; ++j)
                kb[j] = *reinterpret_cast<const hv8*>(
                    ckbase + (size_t)(bt*128 + j*16)*CQK);
            #pragma unroll
            for (int X = 0; X < 4; ++X) {
                float bm[8];
                #pragma unroll
                for (int j = 0; j < 8; ++j) {
                    f32x4 s = __builtin_amdgcn_mfma_f32_16x16x32_f16(
                        kb[j], qf[X], zf, 0, 0, 0);
                    bm[j] = fmaxf(fmaxf(s[0], s[1]), fmaxf(s[2], s[3]));
                }
                float m0 = fmaxf(fmaxf(bm[0], bm[1]), fmaxf(bm[2], bm[3]));
                float m1 = fmaxf(fmaxf(bm[4], bm[5]), fmaxf(bm[6], bm[7]));
                mx[X] = fmaxf(mx[X], fmaxf(m0, m1));
            }
        }
        #pragma unroll
        for (int X = 0; X < 4; ++X) {
            mx[X] = fmaxf(mx[X], __shfl_xor(mx[X], 16, 64));
            mx[X] = fmaxf(mx[X], __shfl_xor(mx[X], 32, 64));
            mneg[X] = -mx[X];
        }
    }

    f32x4 acc[4][8];
    #pragma unroll
    for (int X = 0; X < 4; ++X)
        #pragma unroll
        for (int t = 0; t < 8; ++t) acc[X][t] = zf;
    f32x4 accL[4];
    #pragma unroll
    for (int X = 0; X < 4; ++X) accL[X] = zf;

    // ---- staging: 8 x global_load_lds per wave covers 64 co rows x 64 k.
    const int rl8 = lane >> 3;
    const _Float16* dvs = dv
        + (size_t)(n*CCH + co0 + qw*64 + rl8)*NHW + kg0 + 8*((lane & 7) ^ rl8);
    _Float16* ldsb = (_Float16*)(smem + (g << 14) + qw*8192);

    // swizzled V read offsets (halves)
    const int c0h = ((quad*16) ^ ((l15 & 7) << 4)) >> 1;
    const int c1h = ((64 + quad*16) ^ ((l15 & 7) << 4)) >> 1;

    // S^T/exp for one key tile, all 4 q-groups -> pb (FIXED minit, branch-free)
    auto softmax_tile = [&](const hv8* kf) {
        #pragma unroll
        for (int X = 0; X < 4; ++X) {
            const f32x4 minit = {mneg[X], mneg[X], mneg[X], mneg[X]};
            #pragma unroll
            for (int f = 0; f < 4; ++f) {
                f32x4 s = __builtin_amdgcn_mfma_f32_16x16x32_f16(
                    kf[f], qf[X], minit, 0, 0, 0);
                float p0 = __builtin_amdgcn_exp2f(s[0]);
                float p1 = __builtin_amdgcn_exp2f(s[1]);
                float p2 = __builtin_amdgcn_exp2f(s[2]);
                float p3 = __builtin_amdgcn_exp2f(s[3]);
                fv2 lo = __builtin_amdgcn_cvt_pkrtz(p0, p1);
                fv2 hi = __builtin_amdgcn_cvt_pkrtz(p2, p3);
                uint2 w;
                w.x = __builtin_bit_cast(unsigned, lo);
                w.y = __builtin_bit_cast(unsigned, hi);
                *reinterpret_cast<uint2*>(
                    pb + X*1152 + l15*72 + f*16 + quad*4) = w;
            }
        }
    };

    hv8 pf0[4], pf1[4];
    auto read_pf = [&]() {
        #pragma unroll
        for (int X = 0; X < 4; ++X) {
            pf0[X] = *reinterpret_cast<const hv8*>(pb + X*1152 + l15*72 + quad*8);
            pf1[X] = *reinterpret_cast<const hv8*>(pb + X*1152 + l15*72 + 32 + quad*8);
        }
    };

    auto stage = [&](int kt) {
        #pragma unroll
        for (int j = 0; j < 8; ++j)
            gll16(dvs + (size_t)(j*8)*NHW + kt*64, ldsb + (size_t)(j*8)*64);
    };

    auto load_kf = [&](int key0, hv8* kf) {
        #pragma unroll
        for (int f = 0; f < 4; ++f)
            kf[f] = *reinterpret_cast<const hv8*>(
                ckbase + (size_t)(key0 + f*16)*CQK);
    };

    // ---- prologue: stage V(0) via DMA, softmax(0), pf(0)
    {
        stage(0);
        hv8 kf0[4];
        load_kf(0, kf0);
        softmax_tile(kf0);
        read_pf();
    }
    __syncthreads();    // drains vmcnt -> V(0) resident

    for (int kt = 0; kt < 16; ++kt) {
        hv8 kfn[4];
        if (kt < 15) load_kf((kt + 1)*64, kfn);

        // ---- PV(kt): each V fragment feeds 4 q-groups
        #pragma unroll
        for (int t = 0; t < 8; ++t) {
            const _Float16* vr = vbuf + (t*16 + l15)*64;
            hv8 d0 = *reinterpret_cast<const hv8*>(vr + c0h);
            #pragma unroll
            for (int X = 0; X < 4; ++X)
                acc[X][t] = __builtin_amdgcn_mfma_f32_16x16x32_f16(
                    pf0[X], d0, acc[X][t], 0, 0, 0);
            hv8 d1 = *reinterpret_cast<const hv8*>(vr + c1h);
            #pragma unroll
            for (int X = 0; X < 4; ++X)
                acc[X][t] = __builtin_amdgcn_mfma_f32_16x16x32_f16(
                    pf1[X], d1, acc[X][t], 0, 0, 0);
        }
        #pragma unroll
        for (int X = 0; X < 4; ++X) {
            accL[X] = __builtin_amdgcn_mfma_f32_16x16x32_f16(pf0[X], ones, accL[X], 0, 0, 0);
            accL[X] = __builtin_amdgcn_mfma_f32_16x16x32_f16(pf1[X], ones, accL[X], 0, 0, 0);
        }

        if (kt < 15) {
            softmax_tile(kfn);          // p(kt+1) -> pb (own wave region)
            __syncthreads();            // all done reading V(kt)
            stage(kt + 1);              // DMA V(kt+1) into same buffer
            read_pf();                  // pf(kt+1) from pb (same-wave order)
            __syncthreads();            // drains vmcnt -> V(kt+1) resident
        }
    }

    // ---- align k-group partials to the common max, merge, epilogue
    if (lane < 16) {
        #pragma unroll
        for (int X = 0; X < 4; ++X)
            mbuf[g*128 + qw*64 + X*16 + l15] = -mneg[X];
    }
    __syncthreads();            // all waves past loop; mbuf complete

    {
        #pragma unroll
        for (int X = 0; X < 4; ++X) {
            const int qloc = qw*64 + X*16 + quad*4;
            float4 m0 = *reinterpret_cast<float4*>(&mbuf[0*128 + qloc]);
            float4 m1 = *reinterpret_cast<float4*>(&mbuf[1*128 + qloc]);
            float4 m2 = *reinterpret_cast<float4*>(&mbuf[2*128 + qloc]);
            float4 m3 = *reinterpret_cast<float4*>(&mbuf[3*128 + qloc]);
            float4 mm;
            mm.x = fmaxf(fmaxf(m0.x, m1.x), fmaxf(m2.x, m3.x));
            mm.y = fmaxf(fmaxf(m0.y, m1.y), fmaxf(m2.y, m3.y));
            mm.z = fmaxf(fmaxf(m0.z, m1.z), fmaxf(m2.z, m3.z));
            mm.w = fmaxf(fmaxf(m0.w, m1.w), fmaxf(m2.w, m3.w));
            float4 mo = (g == 0) ? m0 : (g == 1) ? m1 : (g == 2) ? m2 : m3;
            float sc0 = __builtin_amdgcn_exp2f(mo.x - mm.x);
            float sc1 = __builtin_amdgcn_exp2f(mo.y - mm.y);
            float sc2 = __builtin_amdgcn_exp2f(mo.z - mm.z);
            float sc3 = __builtin_amdgcn_exp2f(mo.w - mm.w);
            #pragma unroll
            for (int t = 0; t < 8; ++t) {
                acc[X][t][0] *= sc0; acc[X][t][1] *= sc1;
                acc[X][t][2] *= sc2; acc[X][t][3] *= sc3;
            }
            accL[X][0] *= sc0; accL[X][1] *= sc1;
            accL[X][2] *= sc2; accL[X][3] *= sc3;
        }
    }

    float* buf1 = (float*)smem;                   // [128 co][132 q]
    float* buf2 = (float*)(smem + 67584);

    if (l15 == 0) {
        #pragma unroll
        for (int X = 0; X < 4; ++X)
            *reinterpret_cast<float4*>(&lbuf[g*128 + qw*64 + X*16 + quad*4]) =
                *reinterpret_cast<float4*>(&accL[X]);
    }
    // Round A: g1 -> buf1, g3 -> buf2
    if (g == 1 || g == 3) {
        float* b = (g == 1) ? buf1 : buf2;
        #pragma unroll
        for (int X = 0; X < 4; ++X)
            #pragma unroll
            for (int t = 0; t < 8; ++t)
                *reinterpret_cast<float4*>(
                    &b[(t*16 + l15)*132 + qw*64 + X*16 + quad*4]) =
                    *reinterpret_cast<float4*>(&acc[X][t]);
    }
    __syncthreads();
    if (g == 0 || g == 2) {
        float* b = (g == 0) ? buf1 : buf2;
        #pragma unroll
        for (int X = 0; X < 4; ++X)
            #pragma unroll
            for (int t = 0; t < 8; ++t) {
                float4 p = *reinterpret_cast<float4*>(
                    &b[(t*16 + l15)*132 + qw*64 + X*16 + quad*4]);
                acc[X][t][0] += p.x; acc[X][t][1] += p.y;
                acc[X][t][2] += p.z; acc[X][t][3] += p.w;
            }
    }
    __syncthreads();
    // Round B: g2 -> buf1
    if (g == 2) {
        #pragma unroll
        for (int X = 0; X < 4; ++X)
            #pragma unroll
            for (int t = 0; t < 8; ++t)
                *reinterpret_cast<float4*>(
                    &buf1[(t*16 + l15)*132 + qw*64 + X*16 + quad*4]) =
                    *reinterpret_cast<float4*>(&acc[X][t]);
    }
    __syncthreads();
    if (g == 0) {
        const float alpha = alpha_p[0];
        #pragma unroll
        for (int X = 0; X < 4; ++X) {
            const int qlocX = qw*64 + X*16 + quad*4;
            #pragma unroll
            for (int t = 0; t < 8; ++t) {
                float4 p = *reinterpret_cast<float4*>(
                    &buf1[(t*16 + l15)*132 + qlocX]);
                acc[X][t][0] += p.x; acc[X][t][1] += p.y;
                acc[X][t][2] += p.z; acc[X][t][3] += p.w;
            }
            float4 l0 = *reinterpret_cast<float4*>(&lbuf[0*128 + qlocX]);
            float4 l1 = *reinterpret_cast<float4*>(&lbuf[1*128 + qlocX]);
            float4 l2 = *reinterpret_cast<float4*>(&lbuf[2*128 + qlocX]);
            float4 l3 = *reinterpret_cast<float4*>(&lbuf[3*128 + qlocX]);
            f32x4 rl;
            rl[0] = alpha / (l0.x + l1.x + l2.x + l3.x);
            rl[1] = alpha / (l0.y + l1.y + l2.y + l3.y);
            rl[2] = alpha / (l0.z + l1.z + l2.z + l3.z);
            rl[3] = alpha / (l0.w + l1.w + l2.w + l3.w);
            #pragma unroll
            for (int t = 0; t < 8; ++t) {
                const size_t off =
                    ((size_t)(n*CCH + co0 + t*16 + l15))*NHW + q0b + qlocX;
                float4 av = *reinterpret_cast<const float4*>(a + off);
                float4 o;
                o.x = acc[X][t][0]*rl[0] + av.x;
                o.y = acc[X][t][1]*rl[1] + av.y;
                o.z = acc[X][t][2]*rl[2] + av.z;
                o.w = acc[X][t][3]*rl[3] + av.w;
                *reinterpret_cast<float4*>(out + off) = o;
            }
        }
    }
}

extern "C" void kernel_launch(void* const* d_in, const int* in_sizes, int n_in,
                              void* d_out, int out_size, void* d_ws, size_t ws_size,
                              hipStream_t stream)
{
    const float* a    = (const float*)d_in[0];
    const float* b_w  = (const float*)d_in[1];
    const float* b_b  = (const float*)d_in[2];
    const float* c_w  = (const float*)d_in[3];
    const float* c_b  = (const float*)d_in[4];
    const float* d_w  = (const float*)d_in[5];
    const float* d_b  = (const float*)d_in[6];
    const float* alp  = (const float*)d_in[7];
    float* out = (float*)d_out;

    _Float16* bqT  = (_Float16*)d_ws;                 // [4][4096][32] fp16, 1 MB
    _Float16* ckT  = bqT + (size_t)4*NHW*CQK;         // [4][4096][32] fp16, 1 MB
    _Float16* dv   = ckT + (size_t)4*NHW*CQK;         // [4][256][4096] fp16, 8 MB
    _Float16* Wh   = dv + (size_t)4*CCH*NHW;          // [320][256] fp16, 160 KB

    prep_kernel<<<80, 256, 0, stream>>>(b_w, c_w, d_w, Wh);
    proj_kernel<<<512, 256, 0, stream>>>(a, Wh, b_b, c_b, d_b, bqT, ckT, dv);
    attn_kernel<<<256, 512, 0, stream>>>(bqT, ckT, dv, a, alp, out);
}

// Round 13
// 160.772 us; speedup vs baseline: 1.3772x; 1.0240x over previous
//
#include <hip/hip_runtime.h>
#include <hip/hip_bf16.h>

#define CCH 256
#define CQK 32
#define NHW 4096

typedef float f32x4 __attribute__((ext_vector_type(4)));
typedef _Float16 hv8 __attribute__((ext_vector_type(8)));
typedef _Float16 hv4 __attribute__((ext_vector_type(4)));
typedef __fp16 fv2 __attribute__((ext_vector_type(2)));   // cvt_pkrtz native type

// Direct global->LDS DMA, 16 B/lane. LDS dest = wave-uniform base + lane*16.
typedef __attribute__((address_space(3))) unsigned int lds_u32_t;
typedef __attribute__((address_space(1))) const unsigned int glb_u32_t;
__device__ __forceinline__ void gll16(const _Float16* gp, _Float16* lp) {
    __builtin_amdgcn_global_load_lds((glb_u32_t*)gp, (lds_u32_t*)lp, 16, 0, 0);
}

// ---------------------------------------------------------------------------
// Prep kernel: convert Wall = concat(b_w, c_w, d_w) fp32 -> fp16 [320][256];
// b_w rows prescaled by log2(e) so QK^T comes out in exp2 units. Grid 80 x 256.
// ---------------------------------------------------------------------------
__global__ __launch_bounds__(256) void prep_kernel(
    const float* __restrict__ b_w, const float* __restrict__ c_w,
    const float* __restrict__ d_w, _Float16* __restrict__ Wh)
{
    const int bid = blockIdx.x, tid = threadIdx.x;
    const int idx = (bid * 256 + tid) * 4;
    const int row = idx >> 8, col = idx & 255;
    const float* src = (row < 32) ? (b_w + row * CCH + col)
                     : (row < 64) ? (c_w + (row - 32) * CCH + col)
                                  : (d_w + (row - 64) * CCH + col);
    const float scl = (row < 32) ? 1.4426950408889634f : 1.0f;
    float4 v = *reinterpret_cast<const float4*>(src);
    _Float16* dst = Wh + (size_t)row * CCH + col;
    dst[0] = (_Float16)(v.x * scl); dst[1] = (_Float16)(v.y * scl);
    dst[2] = (_Float16)(v.z * scl); dst[3] = (_Float16)(v.w * scl);
}

// ---------------------------------------------------------------------------
// Projection kernel v2 (R10 verified): MFMA loop + LDS-staged coalesced
// epilogue. Unchanged.
// ---------------------------------------------------------------------------
__global__ __launch_bounds__(256) void proj_kernel(
    const float* __restrict__ a, const _Float16* __restrict__ Wh,
    const float* __restrict__ b_b, const float* __restrict__ c_b,
    const float* __restrict__ d_b,
    _Float16* __restrict__ bqT, _Float16* __restrict__ ckT,
    _Float16* __restrict__ dv)
{
    __shared__ _Float16 aT[32][CCH + 24];   // [pos][ch] input transpose
    __shared__ _Float16 oT[256][34];        // dv staging [ch][pos]
    __shared__ _Float16 pqT[32][34];        // bq staging [pos][ch]
    __shared__ _Float16 pkT[32][34];        // ck staging [pos][ch]

    const int n    = blockIdx.x >> 7;
    const int i0   = (blockIdx.x & 127) << 5;
    const int tid  = threadIdx.x;
    const int lane = tid & 63;
    const int wave = tid >> 6;
    const int l15  = lane & 15;
    const int quad = lane >> 4;

    {
        const float* ap = a + (size_t)(n*CCH + tid)*NHW + i0;
        #pragma unroll
        for (int j = 0; j < 8; ++j) {
            float4 v = *reinterpret_cast<const float4*>(ap + j*4);
            aT[j*4+0][tid] = (_Float16)v.x;
            aT[j*4+1][tid] = (_Float16)v.y;
            aT[j*4+2][tid] = (_Float16)v.z;
            aT[j*4+3][tid] = (_Float16)v.w;
        }
    }
    __syncthreads();

    const f32x4 zf = {0.f, 0.f, 0.f, 0.f};
    f32x4 acc[5][2];
    #pragma unroll
    for (int t = 0; t < 5; ++t) { acc[t][0] = zf; acc[t][1] = zf; }

    const int ch0w = wave * 80;

    #pragma unroll
    for (int ks = 0; ks < 8; ++ks) {
        const int k0 = ks * 32;
        hv8 af0 = *reinterpret_cast<const hv8*>(&aT[l15][k0 + quad*8]);
        hv8 af1 = *reinterpret_cast<const hv8*>(&aT[16 + l15][k0 + quad*8]);
        #pragma unroll
        for (int t = 0; t < 5; ++t) {
            const int ch0 = ch0w + t*16;
            hv8 bf = *reinterpret_cast<const hv8*>(
                Wh + (size_t)(ch0 + l15)*CCH + k0 + quad*8);
            acc[t][0] = __builtin_amdgcn_mfma_f32_16x16x32_f16(af0, bf, acc[t][0], 0, 0, 0);
            acc[t][1] = __builtin_amdgcn_mfma_f32_16x16x32_f16(af1, bf, acc[t][1], 0, 0, 0);
        }
    }

    // ---- stage results into LDS (biases applied here)
    const int posq = quad*4;                // local pos base
    #pragma unroll
    for (int t = 0; t < 5; ++t) {
        const int ch0 = ch0w + t*16;
        if (ch0 < 64) {
            const float* bias_arr = (ch0 < 32) ? b_b : c_b;
            const int    ch       = (ch0 & 31) + l15;
            const float  bias     = bias_arr[ch] *
                ((ch0 < 32) ? 1.4426950408889634f : 1.0f);
            #pragma unroll
            for (int nf = 0; nf < 2; ++nf) {
                #pragma unroll
                for (int r = 0; r < 4; ++r) {
                    const int pos = posq + nf*16 + r;
                    if (ch0 < 32) pqT[pos][ch] = (_Float16)(acc[t][nf][r] + bias);
                    else          pkT[pos][ch] = (_Float16)(acc[t][nf][r] + bias);
                }
            }
        } else {
            const int ch   = ch0 - 64 + l15;
            const float bias = d_b[ch];
            #pragma unroll
            for (int nf = 0; nf < 2; ++nf) {
                hv4 v = { (_Float16)(acc[t][nf][0] + bias),
                          (_Float16)(acc[t][nf][1] + bias),
                          (_Float16)(acc[t][nf][2] + bias),
                          (_Float16)(acc[t][nf][3] + bias) };
                *reinterpret_cast<hv4*>(&oT[ch][posq + nf*16]) = v;
            }
        }
    }
    __syncthreads();

    // ---- coalesced global writes
    {
        const int p   = (tid & 127) >> 2;
        const int seg = (tid & 3) << 3;
        if (tid < 128) {
            *reinterpret_cast<int4*>(
                bqT + ((size_t)n*NHW + i0 + p)*CQK + seg) =
                *reinterpret_cast<const int4*>(&pqT[p][seg]);
        } else {
            *reinterpret_cast<int4*>(
                ckT + ((size_t)n*NHW + i0 + p)*CQK + seg) =
                *reinterpret_cast<const int4*>(&pkT[p][seg]);
        }
    }
    #pragma unroll
    for (int pass = 0; pass < 4; ++pass) {
        const int row = pass*64 + (tid >> 2);
        const int seg = (tid & 3) << 3;
        *reinterpret_cast<int4*>(
            dv + ((size_t)(n*CCH + row))*NHW + i0 + seg) =
            *reinterpret_cast<const int4*>(&oT[row][seg]);
    }
}

// ---------------------------------------------------------------------------
// Pass B v12: WAVE-AUTONOMOUS flash attention -- ZERO in-loop barriers.
// attn was pinned at 76us across 4 softmax variants: per-iter 11.4k cyc vs
// 3.4k of pipe work = barrier lockstep (8 waves x 2 syncthreads x vmcnt(0)
// drains). Restructure: block = 4 waves = 4 k-groups (1024 keys each),
// 64q x 128co per block, KT=32; EACH WAVE OWNS its vbuf (8KB) + pb (5KB) ->
// no cross-wave deps in the loop. Same-wave ordering only:
//   PV reads -> s_waitcnt lgkmcnt(0) (reads retired, buffer reusable)
//   -> DMA stage(kt+1) -> softmax(kt+1) covers DMA latency
//   -> s_waitcnt vmcnt(0) + sched_barrier(0) (DMA landed, same-wave vis).
// LDS 72.7KB -> 2 blocks/CU: co-resident block fills residual stalls.
// Grid 512 (q-tiles of 64), XCD-swizzled. Work conserved (exp x2 as before,
// same MFMA/LDS totals). Batched per-group row-max prologue (R12). End:
// 4-way max-align + O/l merge via LDS with 4 barriers (out of loop).
// smem carve (72704 B): vbuf g*8192 | pb 32768+g*5120 | merge buf1@0,
// buf2@35840 | lbuf@70656 | mbuf@71680.
// ---------------------------------------------------------------------------
__global__ __launch_bounds__(256, 2) void attn_kernel(
    const _Float16* __restrict__ bqT, const _Float16* __restrict__ ckT,
    const _Float16* __restrict__ dv,
    const float* __restrict__ a, const float* __restrict__ alpha_p,
    float* __restrict__ out)
{
    __shared__ __align__(16) char smem[72704];

    // XCD swizzle: 512 blocks, 8 XCDs -> XCD k owns logical [k*64,(k+1)*64)
    const int bx   = ((blockIdx.x & 7) << 6) | (blockIdx.x >> 3);
    const int n    = bx >> 7;
    const int cg   = (bx >> 6) & 1;
    const int qt   = bx & 63;
    const int q0b  = qt << 6;           // block covers 64 q
    const int co0  = cg << 7;           // 128 output channels
    const int tid  = threadIdx.x;
    const int g    = tid >> 6;          // wave = k-group 0..3
    const int lane = tid & 63;
    const int l15  = lane & 15;
    const int quad = lane >> 4;
    const int kg0  = g << 10;           // keys [g*1024, (g+1)*1024)

    _Float16* vbuf = (_Float16*)(smem + g*8192);          // [128 co][32 k] swizzled
    _Float16* pb   = (_Float16*)(smem + 32768 + g*5120);  // 4 slabs of [16][40]
    float*    lbuf = (float*)(smem + 70656);              // [4 g][64 q]
    float*    mbuf = (float*)(smem + 71680);              // [4 g][64 q]

    const f32x4 zf = {0.f, 0.f, 0.f, 0.f};
    const _Float16 one_h = (_Float16)1.0f;
    const hv8 ones = { one_h, one_h, one_h, one_h, one_h, one_h, one_h, one_h };

    // q fragments, 4 groups of 16 q (covers the block's 64 q)
    hv8 qf[4];
    #pragma unroll
    for (int X = 0; X < 4; ++X) {
        const int q = q0b + X*16 + l15;
        qf[X] = *reinterpret_cast<const hv8*>(
            bqT + ((size_t)n*NHW + q)*CQK + quad*8);
    }

    // kf base for this lane within this group's key range
    const _Float16* ckbase = ckT + ((size_t)(n*NHW + kg0 + l15))*CQK + quad*8;

    // ---- batched per-group row-max prologue: 8 batches x 8 kf (1024 keys)
    float mneg[4];
    {
        float mx[4] = {-1e30f, -1e30f, -1e30f, -1e30f};
        #pragma unroll
        for (int bt = 0; bt < 8; ++bt) {
            hv8 kb[8];
            #pragma unroll
            for (int j = 0; j < 8; ++j)
                kb[j] = *reinterpret_cast<const hv8*>(
                    ckbase + (size_t)(bt*128 + j*16)*CQK);
            #pragma unroll
            for (int X = 0; X < 4; ++X) {
                float bm[8];
                #pragma unroll
                for (int j = 0; j < 8; ++j) {
                    f32x4 s = __builtin_amdgcn_mfma_f32_16x16x32_f16(
                        kb[j], qf[X], zf, 0, 0, 0);
                    bm[j] = fmaxf(fmaxf(s[0], s[1]), fmaxf(s[2], s[3]));
                }
                float m0 = fmaxf(fmaxf(bm[0], bm[1]), fmaxf(bm[2], bm[3]));
                float m1 = fmaxf(fmaxf(bm[4], bm[5]), fmaxf(bm[6], bm[7]));
                mx[X] = fmaxf(mx[X], fmaxf(m0, m1));
            }
        }
        #pragma unroll
        for (int X = 0; X < 4; ++X) {
            mx[X] = fmaxf(mx[X], __shfl_xor(mx[X], 16, 64));
            mx[X] = fmaxf(mx[X], __shfl_xor(mx[X], 32, 64));
            mneg[X] = -mx[X];
        }
    }

    f32x4 acc[4][8];
    #pragma unroll
    for (int X = 0; X < 4; ++X)
        #pragma unroll
        for (int t = 0; t < 8; ++t) acc[X][t] = zf;
    f32x4 accL[4];
    #pragma unroll
    for (int X = 0; X < 4; ++X) accL[X] = zf;

    // ---- staging: 8 x gll16 per wave covers 128 co rows x 32 k.
    // lane i: row chunk rl4 = i>>2 (16 rows per gll16, 4 slots of 16B/row);
    // source col pre-permuted by the read swizzle's inverse.
    const int rl4 = lane >> 2;
    const int sl  = lane & 3;
    const _Float16* dvs = dv
        + (size_t)(n*CCH + co0 + rl4)*NHW + kg0 + 8*(sl ^ ((rl4 >> 1) & 3));

    // swizzled V read col (halves): k-slot quad*8 XOR row-hash
    const int c0h = (quad*8) ^ (((l15 >> 1) & 3) << 3);

    // S^T/exp for one 32-key tile, all 4 q-groups -> pb (fixed minit)
    auto softmax_tile = [&](const hv8* kf) {
        #pragma unroll
        for (int X = 0; X < 4; ++X) {
            const f32x4 minit = {mneg[X], mneg[X], mneg[X], mneg[X]};
            #pragma unroll
            for (int f = 0; f < 2; ++f) {
                f32x4 s = __builtin_amdgcn_mfma_f32_16x16x32_f16(
                    kf[f], qf[X], minit, 0, 0, 0);
                float p0 = __builtin_amdgcn_exp2f(s[0]);
                float p1 = __builtin_amdgcn_exp2f(s[1]);
                float p2 = __builtin_amdgcn_exp2f(s[2]);
                float p3 = __builtin_amdgcn_exp2f(s[3]);
                fv2 lo = __builtin_amdgcn_cvt_pkrtz(p0, p1);
                fv2 hi = __builtin_amdgcn_cvt_pkrtz(p2, p3);
                uint2 w;
                w.x = __builtin_bit_cast(unsigned, lo);
                w.y = __builtin_bit_cast(unsigned, hi);
                *reinterpret_cast<uint2*>(
                    pb + X*640 + l15*40 + f*16 + quad*4) = w;
            }
        }
    };

    hv8 pf0[4];
    auto read_pf = [&]() {
        #pragma unroll
        for (int X = 0; X < 4; ++X)
            pf0[X] = *reinterpret_cast<const hv8*>(pb + X*640 + l15*40 + quad*8);
    };

    auto stage = [&](int kt) {
        #pragma unroll
        for (int j = 0; j < 8; ++j)
            gll16(dvs + (size_t)(j*16)*NHW + kt*32, vbuf + j*512);
    };

    auto load_kf = [&](int key0, hv8* kf) {
        #pragma unroll
        for (int f = 0; f < 2; ++f)
            kf[f] = *reinterpret_cast<const hv8*>(
                ckbase + (size_t)(key0 + f*16)*CQK);
    };

    // ---- prologue: stage V(0), softmax(0) under the DMA, wait, pf(0)
    {
        stage(0);
        hv8 kf0[2];
        load_kf(0, kf0);
        softmax_tile(kf0);
        read_pf();
        asm volatile("s_waitcnt vmcnt(0)" ::: "memory");
        __builtin_amdgcn_sched_barrier(0);
    }

    for (int kt = 0; kt < 32; ++kt) {
        hv8 kfn[2];
        if (kt < 31) load_kf((kt + 1)*32, kfn);

        // ---- PV(kt): each V fragment feeds 4 q-groups
        #pragma unroll
        for (int t = 0; t < 8; ++t) {
            hv8 d0 = *reinterpret_cast<const hv8*>(vbuf + (t*16 + l15)*32 + c0h);
            #pragma unroll
            for (int X = 0; X < 4; ++X)
                acc[X][t] = __builtin_amdgcn_mfma_f32_16x16x32_f16(
                    pf0[X], d0, acc[X][t], 0, 0, 0);
        }
        #pragma unroll
        for (int X = 0; X < 4; ++X)
            accL[X] = __builtin_amdgcn_mfma_f32_16x16x32_f16(pf0[X], ones, accL[X], 0, 0, 0);

        if (kt < 31) {
            // all V(kt) ds_reads retired -> buffer reusable (same wave only)
            asm volatile("s_waitcnt lgkmcnt(0)" ::: "memory");
            __builtin_amdgcn_sched_barrier(0);
            stage(kt + 1);              // DMA issue
            softmax_tile(kfn);          // covers DMA latency (MFMA+exp+pb)
            read_pf();                  // pf(kt+1), same-wave LDS order
            asm volatile("s_waitcnt vmcnt(0)" ::: "memory");   // DMA landed
            __builtin_amdgcn_sched_barrier(0);
        }
    }

    // ---- align k-group partials to common max, merge, epilogue
    if (lane < 16) {
        #pragma unroll
        for (int X = 0; X < 4; ++X)
            mbuf[g*64 + X*16 + l15] = -mneg[X];
    }
    __syncthreads();

    {
        #pragma unroll
        for (int X = 0; X < 4; ++X) {
            const int qloc = X*16 + quad*4;
            float4 m0 = *reinterpret_cast<float4*>(&mbuf[0*64 + qloc]);
            float4 m1 = *reinterpret_cast<float4*>(&mbuf[1*64 + qloc]);
            float4 m2 = *reinterpret_cast<float4*>(&mbuf[2*64 + qloc]);
            float4 m3 = *reinterpret_cast<float4*>(&mbuf[3*64 + qloc]);
            float4 mm;
            mm.x = fmaxf(fmaxf(m0.x, m1.x), fmaxf(m2.x, m3.x));
            mm.y = fmaxf(fmaxf(m0.y, m1.y), fmaxf(m2.y, m3.y));
            mm.z = fmaxf(fmaxf(m0.z, m1.z), fmaxf(m2.z, m3.z));
            mm.w = fmaxf(fmaxf(m0.w, m1.w), fmaxf(m2.w, m3.w));
            float4 mo = (g == 0) ? m0 : (g == 1) ? m1 : (g == 2) ? m2 : m3;
            float sc0 = __builtin_amdgcn_exp2f(mo.x - mm.x);
            float sc1 = __builtin_amdgcn_exp2f(mo.y - mm.y);
            float sc2 = __builtin_amdgcn_exp2f(mo.z - mm.z);
            float sc3 = __builtin_amdgcn_exp2f(mo.w - mm.w);
            #pragma unroll
            for (int t = 0; t < 8; ++t) {
                acc[X][t][0] *= sc0; acc[X][t][1] *= sc1;
                acc[X][t][2] *= sc2; acc[X][t][3] *= sc3;
            }
            accL[X][0] *= sc0; accL[X][1] *= sc1;
            accL[X][2] *= sc2; accL[X][3] *= sc3;
        }
    }
    if (lane < 16) {
        // accL[X][r] holds l for q = X*16 + quad*4 + r at l15==0 lanes
        if (l15 == 0) {
            #pragma unroll
            for (int X = 0; X < 4; ++X)
                *reinterpret_cast<float4*>(&lbuf[g*64 + X*16 + quad*4]) =
                    *reinterpret_cast<float4*>(&accL[X]);
        }
    } else if (l15 == 0) {
        #pragma unroll
        for (int X = 0; X < 4; ++X)
            *reinterpret_cast<float4*>(&lbuf[g*64 + X*16 + quad*4]) =
                *reinterpret_cast<float4*>(&accL[X]);
    }
    __syncthreads();

    float* buf1 = (float*)smem;                   // [128 co][68 q]
    float* buf2 = (float*)(smem + 35840);

    // Round A: g1 -> buf1, g3 -> buf2
    if (g == 1 || g == 3) {
        float* b = (g == 1) ? buf1 : buf2;
        #pragma unroll
        for (int X = 0; X < 4; ++X)
            #pragma unroll
            for (int t = 0; t < 8; ++t)
                *reinterpret_cast<float4*>(
                    &b[(t*16 + l15)*68 + X*16 + quad*4]) =
                    *reinterpret_cast<float4*>(&acc[X][t]);
    }
    __syncthreads();
    if (g == 0 || g == 2) {
        float* b = (g == 0) ? buf1 : buf2;
        #pragma unroll
        for (int X = 0; X < 4; ++X)
            #pragma unroll
            for (int t = 0; t < 8; ++t) {
                float4 p = *reinterpret_cast<float4*>(
                    &b[(t*16 + l15)*68 + X*16 + quad*4]);
                acc[X][t][0] += p.x; acc[X][t][1] += p.y;
                acc[X][t][2] += p.z; acc[X][t][3] += p.w;
            }
    }
    __syncthreads();
    // Round B: g2 -> buf1
    if (g == 2) {
        #pragma unroll
        for (int X = 0; X < 4; ++X)
            #pragma unroll
            for (int t = 0; t < 8; ++t)
                *reinterpret_cast<float4*>(
                    &buf1[(t*16 + l15)*68 + X*16 + quad*4]) =
                    *reinterpret_cast<float4*>(&acc[X][t]);
    }
    __syncthreads();
    if (g == 0) {
        const float alpha = alpha_p[0];
        #pragma unroll
        for (int X = 0; X < 4; ++X) {
            const int qloc = X*16 + quad*4;
            #pragma unroll
            for (int t = 0; t < 8; ++t) {
                float4 p = *reinterpret_cast<float4*>(
                    &buf1[(t*16 + l15)*68 + qloc]);
                acc[X][t][0] += p.x; acc[X][t][1] += p.y;
                acc[X][t][2] += p.z; acc[X][t][3] += p.w;
            }
            float4 l0 = *reinterpret_cast<float4*>(&lbuf[0*64 + qloc]);
            float4 l1 = *reinterpret_cast<float4*>(&lbuf[1*64 + qloc]);
            float4 l2 = *reinterpret_cast<float4*>(&lbuf[2*64 + qloc]);
            float4 l3 = *reinterpret_cast<float4*>(&lbuf[3*64 + qloc]);
            f32x4 rl;
            rl[0] = alpha / (l0.x + l1.x + l2.x + l3.x);
            rl[1] = alpha / (l0.y + l1.y + l2.y + l3.y);
            rl[2] = alpha / (l0.z + l1.z + l2.z + l3.z);
            rl[3] = alpha / (l0.w + l1.w + l2.w + l3.w);
            #pragma unroll
            for (int t = 0; t < 8; ++t) {
                const size_t off =
                    ((size_t)(n*CCH + co0 + t*16 + l15))*NHW + q0b + qloc;
                float4 av = *reinterpret_cast<const float4*>(a + off);
                float4 o;
                o.x = acc[X][t][0]*rl[0] + av.x;
                o.y = acc[X][t][1]*rl[1] + av.y;
                o.z = acc[X][t][2]*rl[2] + av.z;
                o.w = acc[X][t][3]*rl[3] + av.w;
                *reinterpret_cast<float4*>(out + off) = o;
            }
        }
    }
}

extern "C" void kernel_launch(void* const* d_in, const int* in_sizes, int n_in,
                              void* d_out, int out_size, void* d_ws, size_t ws_size,
                              hipStream_t stream)
{
    const float* a    = (const float*)d_in[0];
    const float* b_w  = (const float*)d_in[1];
    const float* b_b  = (const float*)d_in[2];
    const float* c_w  = (const float*)d_in[3];
    const float* c_b  = (const float*)d_in[4];
    const float* d_w  = (const float*)d_in[5];
    const float* d_b  = (const float*)d_in[6];
    const float* alp  = (const float*)d_in[7];
    float* out = (float*)d_out;

    _Float16* bqT  = (_Float16*)d_ws;                 // [4][4096][32] fp16, 1 MB
    _Float16* ckT  = bqT + (size_t)4*NHW*CQK;         // [4][4096][32] fp16, 1 MB
    _Float16* dv   = ckT + (size_t)4*NHW*CQK;         // [4][256][4096] fp16, 8 MB
    _Float16* Wh   = dv + (size_t)4*CCH*NHW;          // [320][256] fp16, 160 KB

    prep_kernel<<<80, 256, 0, stream>>>(b_w, c_w, d_w, Wh);
    proj_kernel<<<512, 256, 0, stream>>>(a, Wh, b_b, c_b, d_b, bqT, ckT, dv);
    attn_kernel<<<512, 256, 0, stream>>>(bqT, ckT, dv, a, alp, out);
}